// Round 3
// baseline (2262.602 us; speedup 1.0000x reference)
//
#include <hip/hip_runtime.h>

// GAWADecoder on MI355X (gfx950). All tensors fp32 in global; bf16 MFMA inside.
// R5 post-mortem: weight-stationary + cross-block flags removed the traffic
// (FETCH 4.3GB->305MB) but NOT the time -> loop is latency/sync-bound, and
// agent-scope fences on 8-XCD gfx950 are L2 writeback/invalidate storms.
// R6: back to R4's fence-free block-local structure with the two measured
// diseases fixed:
//  (a) VGPR cap 128 (__launch_bounds__(1024,4)) + explicit reg-double-buffered
//      software pipeline on the weight streams (depth-2 lookahead, ~4 b128 in
//      flight/wave; 16 waves/CU ~ 64KB outstanding > the ~28KB needed for L2).
//  (b) h1all archive stores are NONTEMPORAL so 67MB of streaming writes stop
//      evicting the 1.18MB weight set from L2 (R4's 43% miss / 4.3GB FETCH).
//  State slimmed: cg = gword + cproj fused at load time (12 regs, refreshed
//  per step during phase B where its latency hides under the w_ih1 stream).

typedef __bf16 bf16;
typedef __attribute__((ext_vector_type(8))) __bf16 bf16x8;
typedef __attribute__((ext_vector_type(4))) __bf16 bf16x4;
typedef __attribute__((ext_vector_type(4))) float fx4;

#define MFMA16(a, b, c) __builtin_amdgcn_mfma_f32_16x16x32_bf16(a, b, c, 0, 0, 0)

__device__ __forceinline__ float sigm(float x) { return 1.0f / (1.0f + expf(-x)); }

// load 8 consecutive fp32, round to bf16x8 (MFMA operand)
__device__ __forceinline__ bf16x8 cvt8(const float* __restrict__ p) {
    float4 u = ((const float4*)p)[0];
    float4 v = ((const float4*)p)[1];
    bf16x8 r;
    r[0] = (bf16)u.x; r[1] = (bf16)u.y; r[2] = (bf16)u.z; r[3] = (bf16)u.w;
    r[4] = (bf16)v.x; r[5] = (bf16)v.y; r[6] = (bf16)v.z; r[7] = (bf16)v.w;
    return r;
}

// bf16x8 h + fp32[8] -> bf16x8 (logits A-fragment: h1 + attn_out)
__device__ __forceinline__ bf16x8 addcvt8(bf16x8 h, const float* __restrict__ p) {
    float4 u = ((const float4*)p)[0];
    float4 v = ((const float4*)p)[1];
    bf16x8 r;
    r[0] = (bf16)((float)h[0] + u.x); r[1] = (bf16)((float)h[1] + u.y);
    r[2] = (bf16)((float)h[2] + u.z); r[3] = (bf16)((float)h[3] + u.w);
    r[4] = (bf16)((float)h[4] + v.x); r[5] = (bf16)((float)h[5] + v.y);
    r[6] = (bf16)((float)h[6] + v.z); r[7] = (bf16)((float)h[7] + v.w);
    return r;
}

// ---------------------------------------------------------------------------
__global__ void f2b(const float* __restrict__ s, bf16* __restrict__ d, int n) {
    int i = (blockIdx.x * 256 + threadIdx.x) * 4;
    if (i >= n) return;
    float4 v = *(const float4*)(s + i);
    bf16x4 o;
    o[0] = (bf16)v.x; o[1] = (bf16)v.y; o[2] = (bf16)v.z; o[3] = (bf16)v.w;
    *(bf16x4*)(d + i) = o;
}

// ---------------------------------------------------------------------------
// out[M,N] = act(A[M,K] @ W[N,K]^T + bias), fp32 in global; bf16 MFMA inside.
// ---------------------------------------------------------------------------
__global__ __launch_bounds__(256, 4) void gemm_bt(
    const float* __restrict__ A, int lda,
    const float* __restrict__ W, int ldw,
    const float* __restrict__ bias,
    float* __restrict__ out, int ldo, int act_tanh, int K)
{
    const int tid  = threadIdx.x;
    const int wid  = tid >> 6;
    const int lane = tid & 63;
    const int quad = lane >> 4;
    const int l16  = lane & 15;
    const int m0   = blockIdx.x * 32;
    const int n0   = blockIdx.y * 256 + wid * 64;

    fx4 acc[4][2];
#pragma unroll
    for (int j = 0; j < 4; ++j) {
        acc[j][0] = fx4{0.f, 0.f, 0.f, 0.f};
        acc[j][1] = fx4{0.f, 0.f, 0.f, 0.f};
    }

    const float* a0p = A + (size_t)(m0 + l16) * lda + quad * 8;
    const float* a1p = A + (size_t)(m0 + 16 + l16) * lda + quad * 8;

    for (int k0 = 0; k0 < K; k0 += 32) {
        bf16x8 a0 = cvt8(a0p + k0);
        bf16x8 a1 = cvt8(a1p + k0);
#pragma unroll
        for (int j = 0; j < 4; ++j) {
            bf16x8 b = cvt8(W + (size_t)(n0 + j * 16 + l16) * ldw + k0 + quad * 8);
            acc[j][0] = MFMA16(a0, b, acc[j][0]);
            acc[j][1] = MFMA16(a1, b, acc[j][1]);
        }
    }

#pragma unroll
    for (int j = 0; j < 4; ++j) {
        int n = n0 + j * 16 + l16;
        float bv = bias ? bias[n] : 0.0f;
#pragma unroll
        for (int rt = 0; rt < 2; ++rt)
#pragma unroll
            for (int r = 0; r < 4; ++r) {
                int m = m0 + rt * 16 + quad * 4 + r;
                float v = acc[j][rt][r] + bv;
                if (act_tanh) v = tanhf(v);
                out[(size_t)m * ldo + n] = v;
            }
    }
}

// ---------------------------------------------------------------------------
// Persistent recurrent kernel. 256 blocks x 1024 thr (16 waves, 1 block/CU,
// VGPR cap 128 via __launch_bounds__(1024,4)), 16 batch rows/block.
// Two barriers/step, block-local LDS ping-pong h-exchange (no fences):
//   phase A: gh0 = h0(t-1)@w_hh0^T AND gh1 = h1(t-1)@w_hh1^T, one fused
//            reg-double-buffered k-loop (4 global b128 in flight) -> layer-0
//            gates -> write h0(t) to partner buffer -> barrier.
//   phase B: gi1 = h0(t)@w_ih1^T (pipelined) overlapped with the next step's
//            cg = gword + cproj[id] gather -> layer-1 gates (uses phase-A gh1)
//            -> write h1(t) slice + NT-store to h1all archive -> barrier.
// Wave w owns cols [w*16,w*16+16); each lane holds rows quad*4..+3 x 1 col.
// ---------------------------------------------------------------------------
__global__ __launch_bounds__(1024, 4) void decoder_loop(
    const int*   __restrict__ tgt,      // (4096,32)
    const float* __restrict__ h0i,      // (4096,256)
    const float* __restrict__ gword,    // (4096,768) eword part of gi0 (+b_ih0)
    const float* __restrict__ cproj,    // (256,768)  char_emb @ w_ih0[:,:64]^T
    const bf16*  __restrict__ w_hh0, const float* __restrict__ b_hh0,
    const bf16*  __restrict__ w_ih1, const float* __restrict__ b_ih1,
    const bf16*  __restrict__ w_hh1, const float* __restrict__ b_hh1,
    bf16* __restrict__ h1all)           // (4096,32,256) bf16
{
    __shared__ __align__(16) bf16 hb0[2][16][264];   // +8 pad
    __shared__ __align__(16) bf16 hb1[2][16][264];

    const int tid  = threadIdx.x;
    const int wid  = tid >> 6;     // 0..15
    const int lane = tid & 63;
    const int quad = lane >> 4;
    const int l16  = lane & 15;
    const int row0 = blockIdx.x * 16;
    const int col  = wid * 16 + l16;
    const int rw   = quad * 4;     // lane's first of 4 rows

    // step-invariant per-lane state
    float h0m[4], h1m[4], cg[3][4];
    float bh0[3], bi1[3], bh1[3];
#pragma unroll
    for (int g = 0; g < 3; ++g) {
        bh0[g] = b_hh0[g * 256 + col];
        bi1[g] = b_ih1[g * 256 + col];
        bh1[g] = b_hh1[g * 256 + col];
    }
#pragma unroll
    for (int r = 0; r < 4; ++r) {
        int row = row0 + rw + r;
        float v = h0i[(size_t)row * 256 + col];
        h0m[r] = v; h1m[r] = v;
        bf16 bv = (bf16)v;
        hb0[0][rw + r][col] = bv; hb1[0][rw + r][col] = bv;
        // t=0 char input is BOS(=1): cg = gword + cproj[BOS]
#pragma unroll
        for (int g = 0; g < 3; ++g)
            cg[g][r] = cproj[(size_t)768 + g * 256 + col]
                     + gword[(size_t)row * 768 + g * 256 + col];
    }

    // byte offsets into the (768x256) bf16 weight mats (same geometry all 3)
    const char* Wp0 = (const char*)w_hh0;
    const char* Wp1 = (const char*)w_ih1;
    const char* Wp2 = (const char*)w_hh1;
    int woff[3];
#pragma unroll
    for (int g = 0; g < 3; ++g)
        woff[g] = ((g * 256 + col) * 256 + quad * 8) * 2;

    __syncthreads();   // initial hb0[0]/hb1[0] visible

    for (int t = 0; t < 32; ++t) {
        const int p = t & 1, q = p ^ 1;

        // ids for step t+1 (pure input; issued early, consumed in phase B)
        int nid[4];
#pragma unroll
        for (int r = 0; r < 4; ++r)
            nid[r] = tgt[(row0 + rw + r) * 32 + t];

        // -------- phase A: gh0 = h0@w_hh0^T ; gh1 = h1@w_hh1^T (fused, piped) --
        fx4 g0[3], g1[3];
#pragma unroll
        for (int g = 0; g < 3; ++g) {
            g0[g] = fx4{0.f, 0.f, 0.f, 0.f};
            g1[g] = fx4{0.f, 0.f, 0.f, 0.f};
        }
        bf16x8 av[2], cv[2], wb0[2], wb2[2];
        av[0] = *(const bf16x8*)&hb0[p][l16][quad * 8];
        cv[0] = *(const bf16x8*)&hb1[p][l16][quad * 8];
        av[1] = *(const bf16x8*)&hb0[p][l16][32 + quad * 8];
        cv[1] = *(const bf16x8*)&hb1[p][l16][32 + quad * 8];
        wb0[0] = *(const bf16x8*)(Wp0 + woff[0]);            // stage 0: (k0,g0)
        wb2[0] = *(const bf16x8*)(Wp2 + woff[0]);
        wb0[1] = *(const bf16x8*)(Wp0 + woff[1]);            // stage 1: (k0,g1)
        wb2[1] = *(const bf16x8*)(Wp2 + woff[1]);
#pragma unroll
        for (int kk = 0; kk < 8; ++kk) {
            bf16x8 au = av[kk & 1], cu = cv[kk & 1];
            if (kk < 6) {
                av[kk & 1] = *(const bf16x8*)&hb0[p][l16][(kk + 2) * 32 + quad * 8];
                cv[kk & 1] = *(const bf16x8*)&hb1[p][l16][(kk + 2) * 32 + quad * 8];
            }
#pragma unroll
            for (int g = 0; g < 3; ++g) {
                const int s = kk * 3 + g;
                bf16x8 b0 = wb0[s & 1], b2 = wb2[s & 1];
                if (s + 2 < 24) {                       // depth-2 lookahead
                    const int g2 = (s + 2) % 3, k2 = (s + 2) / 3;
                    wb0[s & 1] = *(const bf16x8*)(Wp0 + woff[g2] + k2 * 64);
                    wb2[s & 1] = *(const bf16x8*)(Wp2 + woff[g2] + k2 * 64);
                }
                g0[g] = MFMA16(au, b0, g0[g]);
                g1[g] = MFMA16(cu, b2, g1[g]);
            }
        }
        // layer-0 gates -> h0(t) into partner buffer
#pragma unroll
        for (int r = 0; r < 4; ++r) {
            float rr = sigm(cg[0][r] + g0[0][r] + bh0[0]);
            float zz = sigm(cg[1][r] + g0[1][r] + bh0[1]);
            float nn = tanhf(cg[2][r] + rr * (g0[2][r] + bh0[2]));
            h0m[r] = (1.0f - zz) * nn + zz * h0m[r];
            hb0[q][rw + r][col] = (bf16)h0m[r];
        }
        __syncthreads();   // B1: h0(t) visible; done with hb0[p]/hb1[p]

        // -------- phase B: gi1 = h0(t)@w_ih1^T (piped), cg-gather overlapped --
        float cgn[3][4];
#pragma unroll
        for (int g = 0; g < 3; ++g)
#pragma unroll
            for (int r = 0; r < 4; ++r)
                cgn[g][r] = cproj[(size_t)nid[r] * 768 + g * 256 + col]
                          + gword[(size_t)(row0 + rw + r) * 768 + g * 256 + col];

        fx4 gi[3];
#pragma unroll
        for (int g = 0; g < 3; ++g) gi[g] = fx4{0.f, 0.f, 0.f, 0.f};
        bf16x8 bv2[2], wb1[2];
        bv2[0] = *(const bf16x8*)&hb0[q][l16][quad * 8];
        bv2[1] = *(const bf16x8*)&hb0[q][l16][32 + quad * 8];
        wb1[0] = *(const bf16x8*)(Wp1 + woff[0]);
        wb1[1] = *(const bf16x8*)(Wp1 + woff[1]);
#pragma unroll
        for (int kk = 0; kk < 8; ++kk) {
            bf16x8 au = bv2[kk & 1];
            if (kk < 6)
                bv2[kk & 1] = *(const bf16x8*)&hb0[q][l16][(kk + 2) * 32 + quad * 8];
#pragma unroll
            for (int g = 0; g < 3; ++g) {
                const int s = kk * 3 + g;
                bf16x8 b = wb1[s & 1];
                if (s + 2 < 24) {
                    const int g2 = (s + 2) % 3, k2 = (s + 2) / 3;
                    wb1[s & 1] = *(const bf16x8*)(Wp1 + woff[g2] + k2 * 64);
                }
                gi[g] = MFMA16(au, b, gi[g]);
            }
        }
        // layer-1 gates (g1 = gh1 from phase A) -> h1(t)
#pragma unroll
        for (int r = 0; r < 4; ++r) {
            float rr = sigm(gi[0][r] + bi1[0] + g1[0][r] + bh1[0]);
            float zz = sigm(gi[1][r] + bi1[1] + g1[1][r] + bh1[1]);
            float nn = tanhf(gi[2][r] + bi1[2] + rr * (g1[2][r] + bh1[2]));
            h1m[r] = (1.0f - zz) * nn + zz * h1m[r];
            bf16 hv = (bf16)h1m[r];
            hb1[q][rw + r][col] = hv;
            // NT store: don't let the 67MB archive evict weights from L2
            __builtin_nontemporal_store(
                hv, &h1all[((size_t)(row0 + rw + r) * 32 + t) * 256 + col]);
        }
#pragma unroll
        for (int g = 0; g < 3; ++g)
#pragma unroll
            for (int r = 0; r < 4; ++r) cg[g][r] = cgn[g][r];

        __syncthreads();   // B2: h1(t) visible
    }
}

// ---------------------------------------------------------------------------
// Final logits: out[m,v] = (h1[m,:] + a2[m>>5,:]) @ pw^T + pb[v],  M=131072.
// ---------------------------------------------------------------------------
__global__ __launch_bounds__(256, 4) void logits_final(
    const bf16*  __restrict__ h1,    // (131072,256) bf16
    const float* __restrict__ a2,    // (4096,256) attn_out (fp32)
    const bf16*  __restrict__ pw,    // (256,256) bf16
    const float* __restrict__ pb,    // (256,)
    float* __restrict__ out)         // (131072,256)
{
    const int tid  = threadIdx.x;
    const int wid  = tid >> 6;
    const int lane = tid & 63;
    const int quad = lane >> 4;
    const int l16  = lane & 15;
    const int m0   = blockIdx.x * 32;
    const int n0   = wid * 64;
    const int b    = m0 >> 5;          // all 32 rows share one batch index

    fx4 acc[4][2];
#pragma unroll
    for (int j = 0; j < 4; ++j) {
        acc[j][0] = fx4{0.f, 0.f, 0.f, 0.f};
        acc[j][1] = fx4{0.f, 0.f, 0.f, 0.f};
    }

    for (int k0 = 0; k0 < 256; k0 += 32) {
        bf16x8 h0 = *(const bf16x8*)(h1 + (size_t)(m0 + l16) * 256 + k0 + quad * 8);
        bf16x8 h1v = *(const bf16x8*)(h1 + (size_t)(m0 + 16 + l16) * 256 + k0 + quad * 8);
        const float* ap = a2 + (size_t)b * 256 + k0 + quad * 8;
        bf16x8 a0 = addcvt8(h0, ap);
        bf16x8 a1 = addcvt8(h1v, ap);
#pragma unroll
        for (int j = 0; j < 4; ++j) {
            bf16x8 bb = *(const bf16x8*)(pw + (size_t)(n0 + j * 16 + l16) * 256 + k0 + quad * 8);
            acc[j][0] = MFMA16(a0, bb, acc[j][0]);
            acc[j][1] = MFMA16(a1, bb, acc[j][1]);
        }
    }

#pragma unroll
    for (int j = 0; j < 4; ++j) {
        int n = n0 + j * 16 + l16;
        float bv = pb[n];
#pragma unroll
        for (int rt = 0; rt < 2; ++rt)
#pragma unroll
            for (int r = 0; r < 4; ++r) {
                int m = m0 + rt * 16 + quad * 4 + r;
                out[(size_t)m * 256 + n] = acc[j][rt][r] + bv;
            }
    }
}

// ---------------------------------------------------------------------------
extern "C" void kernel_launch(void* const* d_in, const int* in_sizes, int n_in,
                              void* d_out, int out_size, void* d_ws, size_t ws_size,
                              hipStream_t stream)
{
    const float* eword      = (const float*)d_in[0];
    const int*   tgt        = (const int*)  d_in[1];
    const float* char_emb   = (const float*)d_in[2];
    const float* ew_w       = (const float*)d_in[3];
    const float* ew_b       = (const float*)d_in[4];
    const float* w_ih0      = (const float*)d_in[5];   // (768, 832)
    const float* w_hh0      = (const float*)d_in[6];
    const float* b_ih0      = (const float*)d_in[7];
    const float* b_hh0      = (const float*)d_in[8];
    const float* w_ih1      = (const float*)d_in[9];
    const float* w_hh1      = (const float*)d_in[10];
    const float* b_ih1      = (const float*)d_in[11];
    const float* b_hh1      = (const float*)d_in[12];
    const float* attn_in_w  = (const float*)d_in[13];  // wq|wk|wv (q,k dead)
    const float* attn_in_b  = (const float*)d_in[14];
    const float* attn_out_w = (const float*)d_in[15];
    const float* attn_out_b = (const float*)d_in[16];
    // d_in[17..18] key_w/key_b dead (len-1 softmax)
    const float* val_w      = (const float*)d_in[19];
    const float* val_b      = (const float*)d_in[20];
    const float* proj_w     = (const float*)d_in[21];
    const float* proj_b     = (const float*)d_in[22];

    char* ws = (char*)d_ws;
    float* h0i   = (float*)ws;  ws += (size_t)4096 * 256 * 4;   //  4 MB
    float* gwrd  = (float*)ws;  ws += (size_t)4096 * 768 * 4;   // 12 MB
    float* cproj = (float*)ws;  ws += (size_t)256  * 768 * 4;   // .75 MB
    float* a2    = (float*)ws;  ws += (size_t)4096 * 256 * 4;   //  4 MB
    float* buf1  = (float*)ws;  ws += (size_t)4096 * 256 * 4;   //  4 MB (t1)
    float* buf2  = (float*)ws;  ws += (size_t)4096 * 256 * 4;   //  4 MB (ev)
    bf16*  wbhh0 = (bf16*)ws;   ws += (size_t)768 * 256 * 2;
    bf16*  wbih1 = (bf16*)ws;   ws += (size_t)768 * 256 * 2;
    bf16*  wbhh1 = (bf16*)ws;   ws += (size_t)768 * 256 * 2;
    bf16*  wbprj = (bf16*)ws;   ws += (size_t)256 * 256 * 2;
    bf16*  h1all = (bf16*)ws;   ws += (size_t)4096 * 32 * 256 * 2;  // 67 MB

    dim3 blk(256);
    f2b<<<dim3(192), blk, 0, stream>>>(w_hh0, wbhh0, 768 * 256);
    f2b<<<dim3(192), blk, 0, stream>>>(w_ih1, wbih1, 768 * 256);
    f2b<<<dim3(192), blk, 0, stream>>>(w_hh1, wbhh1, 768 * 256);
    f2b<<<dim3(64),  blk, 0, stream>>>(proj_w, wbprj, 256 * 256);

    // h0 = tanh(eword @ ew_w^T + ew_b)
    gemm_bt<<<dim3(128, 1), blk, 0, stream>>>(eword, 768, ew_w, 768, ew_b, h0i, 256, 1, 768);
    // gword = eword @ w_ih0[:,64:]^T + b_ih0
    gemm_bt<<<dim3(128, 3), blk, 0, stream>>>(eword, 768, w_ih0 + 64, 832, b_ih0, gwrd, 768, 0, 768);
    // cproj = char_emb @ w_ih0[:,:64]^T   (PAD row of char_emb is zero)
    gemm_bt<<<dim3(8, 3),   blk, 0, stream>>>(char_emb, 64, w_ih0, 832, nullptr, cproj, 768, 0, 64);
    // attention chain (static): t1 = ew@vw^T+vb; ev = t1@wv^T+bv; a2 = ev@ao^T+ab
    gemm_bt<<<dim3(128, 1), blk, 0, stream>>>(eword, 768, val_w, 768, val_b, buf1, 256, 0, 768);
    gemm_bt<<<dim3(128, 1), blk, 0, stream>>>(buf1, 256, attn_in_w + 512 * 256, 256, attn_in_b + 512, buf2, 256, 0, 256);
    gemm_bt<<<dim3(128, 1), blk, 0, stream>>>(buf2, 256, attn_out_w, 256, attn_out_b, a2, 256, 0, 256);

    // recurrent decode (h1 trajectory to global), 256 blocks x 16 rows
    decoder_loop<<<dim3(256), dim3(1024), 0, stream>>>(
        tgt, h0i, gwrd, cproj,
        wbhh0, b_hh0, wbih1, b_ih1, wbhh1, b_hh1, h1all);

    // batched logits: out = (h1 + a2) @ pw^T + pb
    logits_final<<<dim3(4096), blk, 0, stream>>>(h1all, a2, wbprj, proj_b, (float*)d_out);
}

// Round 5
// 2236.385 us; speedup vs baseline: 1.0117x; 1.0117x over previous
//
#include <hip/hip_runtime.h>

// GAWADecoder on MI355X (gfx950). All tensors fp32 in global; bf16 MFMA inside.
// R6 post-mortem: all loop variants (R3-R6) stuck at ~1.6ms because the weight
// matrices are stored [gate_col][k] with 512B column stride -> every wave-wide
// weight load touches 16 scattered cache lines. ~18K scattered line-requests
// per CU per step = request-rate wall; also explains the 44% L2 miss on a
// 1.18MB read-only set (no sequential locality, 32 drifting blocks/XCD).
// R7: REPACK the weights into per-wave linear slabs ([wave][kchunk][gate]
// [l16][quad][8], 24KB/wave/mat) so each weight load is a contiguous 1KB
// 8-line burst and each wave's per-step stream is a sequential 24KB read.
// Loop structure unchanged from R6 (fence-free, 2 barriers/step, 256x16).
// (R7 resubmit: round-4 bench was an infra failure, kernel never measured.)

typedef __bf16 bf16;
typedef __attribute__((ext_vector_type(8))) __bf16 bf16x8;
typedef __attribute__((ext_vector_type(4))) __bf16 bf16x4;
typedef __attribute__((ext_vector_type(4))) float fx4;

#define MFMA16(a, b, c) __builtin_amdgcn_mfma_f32_16x16x32_bf16(a, b, c, 0, 0, 0)

__device__ __forceinline__ float sigm(float x) { return 1.0f / (1.0f + expf(-x)); }

// load 8 consecutive fp32, round to bf16x8 (MFMA operand)
__device__ __forceinline__ bf16x8 cvt8(const float* __restrict__ p) {
    float4 u = ((const float4*)p)[0];
    float4 v = ((const float4*)p)[1];
    bf16x8 r;
    r[0] = (bf16)u.x; r[1] = (bf16)u.y; r[2] = (bf16)u.z; r[3] = (bf16)u.w;
    r[4] = (bf16)v.x; r[5] = (bf16)v.y; r[6] = (bf16)v.z; r[7] = (bf16)v.w;
    return r;
}

// bf16x8 h + fp32[8] -> bf16x8 (logits A-fragment: h1 + attn_out)
__device__ __forceinline__ bf16x8 addcvt8(bf16x8 h, const float* __restrict__ p) {
    float4 u = ((const float4*)p)[0];
    float4 v = ((const float4*)p)[1];
    bf16x8 r;
    r[0] = (bf16)((float)h[0] + u.x); r[1] = (bf16)((float)h[1] + u.y);
    r[2] = (bf16)((float)h[2] + u.z); r[3] = (bf16)((float)h[3] + u.w);
    r[4] = (bf16)((float)h[4] + v.x); r[5] = (bf16)((float)h[5] + v.y);
    r[6] = (bf16)((float)h[6] + v.z); r[7] = (bf16)((float)h[7] + v.w);
    return r;
}

// ---------------------------------------------------------------------------
__global__ void f2b(const float* __restrict__ s, bf16* __restrict__ d, int n) {
    int i = (blockIdx.x * 256 + threadIdx.x) * 4;
    if (i >= n) return;
    float4 v = *(const float4*)(s + i);
    bf16x4 o;
    o[0] = (bf16)v.x; o[1] = (bf16)v.y; o[2] = (bf16)v.z; o[3] = (bf16)v.w;
    *(bf16x4*)(d + i) = o;
}

// ---------------------------------------------------------------------------
// Repack a (768,256) fp32 weight matrix into per-wave linear bf16 slabs:
//   dst elem idx = ((((w*8 + c)*3 + g)*16 + l16)*4 + quad)*8 + e
// where src gate-col gc = g*256 + w*16 + l16, src k = c*32 + quad*8 + e.
// Each wave w's slab is 12288 elems (24KB) consumed strictly sequentially
// (kk-major, gate-minor) by the decoder loop; every wave-wide load in the
// loop reads a contiguous 1KB from this image.
// ---------------------------------------------------------------------------
__global__ void wpack(const float* __restrict__ src, bf16* __restrict__ dst) {
    int gid = blockIdx.x * 256 + threadIdx.x;     // 768*32 pieces of 8 elems
    if (gid >= 768 * 32) return;
    int gc = gid >> 5, piece = gid & 31;
    int g = gc >> 8, rem = gc & 255, w = rem >> 4, l16 = rem & 15;
    int c = piece >> 2, quad = piece & 3;
    bf16x8 v = cvt8(src + (size_t)gc * 256 + piece * 8);
    size_t d = (size_t)w * 12288 + (size_t)(c * 3 + g) * 512 + l16 * 32 + quad * 8;
    *(bf16x8*)(dst + d) = v;
}

// ---------------------------------------------------------------------------
// out[M,N] = act(A[M,K] @ W[N,K]^T + bias), fp32 in global; bf16 MFMA inside.
// ---------------------------------------------------------------------------
__global__ __launch_bounds__(256, 4) void gemm_bt(
    const float* __restrict__ A, int lda,
    const float* __restrict__ W, int ldw,
    const float* __restrict__ bias,
    float* __restrict__ out, int ldo, int act_tanh, int K)
{
    const int tid  = threadIdx.x;
    const int wid  = tid >> 6;
    const int lane = tid & 63;
    const int quad = lane >> 4;
    const int l16  = lane & 15;
    const int m0   = blockIdx.x * 32;
    const int n0   = blockIdx.y * 256 + wid * 64;

    fx4 acc[4][2];
#pragma unroll
    for (int j = 0; j < 4; ++j) {
        acc[j][0] = fx4{0.f, 0.f, 0.f, 0.f};
        acc[j][1] = fx4{0.f, 0.f, 0.f, 0.f};
    }

    const float* a0p = A + (size_t)(m0 + l16) * lda + quad * 8;
    const float* a1p = A + (size_t)(m0 + 16 + l16) * lda + quad * 8;

    for (int k0 = 0; k0 < K; k0 += 32) {
        bf16x8 a0 = cvt8(a0p + k0);
        bf16x8 a1 = cvt8(a1p + k0);
#pragma unroll
        for (int j = 0; j < 4; ++j) {
            bf16x8 b = cvt8(W + (size_t)(n0 + j * 16 + l16) * ldw + k0 + quad * 8);
            acc[j][0] = MFMA16(a0, b, acc[j][0]);
            acc[j][1] = MFMA16(a1, b, acc[j][1]);
        }
    }

#pragma unroll
    for (int j = 0; j < 4; ++j) {
        int n = n0 + j * 16 + l16;
        float bv = bias ? bias[n] : 0.0f;
#pragma unroll
        for (int rt = 0; rt < 2; ++rt)
#pragma unroll
            for (int r = 0; r < 4; ++r) {
                int m = m0 + rt * 16 + quad * 4 + r;
                float v = acc[j][rt][r] + bv;
                if (act_tanh) v = tanhf(v);
                out[(size_t)m * ldo + n] = v;
            }
    }
}

// ---------------------------------------------------------------------------
// Persistent recurrent kernel. 256 blocks x 1024 thr (16 waves, 1 block/CU),
// 16 batch rows/block. Two barriers/step, block-local LDS ping-pong.
// Weight reads come from the wpack'd per-wave linear slabs: each load is a
// contiguous 1KB wave burst; per step each wave streams 3 x 24KB sequentially.
// k-chunk-granular register double-buffer keeps ~6 loads in flight.
// ---------------------------------------------------------------------------
__global__ __launch_bounds__(1024, 4) void decoder_loop(
    const int*   __restrict__ tgt,      // (4096,32)
    const float* __restrict__ h0i,      // (4096,256)
    const float* __restrict__ gword,    // (4096,768) eword part of gi0 (+b_ih0)
    const float* __restrict__ cproj,    // (256,768)  char_emb @ w_ih0[:,:64]^T
    const bf16*  __restrict__ w_hh0p, const float* __restrict__ b_hh0,
    const bf16*  __restrict__ w_ih1p, const float* __restrict__ b_ih1,
    const bf16*  __restrict__ w_hh1p, const float* __restrict__ b_hh1,
    bf16* __restrict__ h1all)           // (4096,32,256) bf16
{
    __shared__ __align__(16) bf16 hb0[2][16][264];   // +8 pad
    __shared__ __align__(16) bf16 hb1[2][16][264];

    const int tid  = threadIdx.x;
    const int wid  = tid >> 6;     // 0..15
    const int lane = tid & 63;
    const int quad = lane >> 4;
    const int l16  = lane & 15;
    const int row0 = blockIdx.x * 16;
    const int col  = wid * 16 + l16;
    const int rw   = quad * 4;     // lane's first of 4 rows

    // per-wave linear slab bases (lane-fixed offset inside each 1KB chunk)
    const bf16* pW0 = w_hh0p + (size_t)wid * 12288 + l16 * 32 + quad * 8;
    const bf16* pW1 = w_ih1p + (size_t)wid * 12288 + l16 * 32 + quad * 8;
    const bf16* pW2 = w_hh1p + (size_t)wid * 12288 + l16 * 32 + quad * 8;

    // persistent per-lane state (small: ~30 regs)
    float h0m[4], h1m[4], cg[3][4];
    float bh0[3], bi1[3], bh1[3];
#pragma unroll
    for (int g = 0; g < 3; ++g) {
        bh0[g] = b_hh0[g * 256 + col];
        bi1[g] = b_ih1[g * 256 + col];
        bh1[g] = b_hh1[g * 256 + col];
    }
#pragma unroll
    for (int r = 0; r < 4; ++r) {
        int row = row0 + rw + r;
        float v = h0i[(size_t)row * 256 + col];
        h0m[r] = v; h1m[r] = v;
        bf16 bv = (bf16)v;
        hb0[0][rw + r][col] = bv; hb1[0][rw + r][col] = bv;
        // t=0 char input is BOS(=1): cg = gword + cproj[BOS]
#pragma unroll
        for (int g = 0; g < 3; ++g)
            cg[g][r] = cproj[(size_t)768 + g * 256 + col]
                     + gword[(size_t)row * 768 + g * 256 + col];
    }

    __syncthreads();   // initial hb0[0]/hb1[0] visible

    for (int t = 0; t < 32; ++t) {
        const int p = t & 1, q = p ^ 1;

        // -------- phase A: gh0 = h0@w_hh0^T ; gh1 = h1@w_hh1^T --------
        fx4 g0[3], g1[3];
#pragma unroll
        for (int g = 0; g < 3; ++g) {
            g0[g] = fx4{0.f, 0.f, 0.f, 0.f};
            g1[g] = fx4{0.f, 0.f, 0.f, 0.f};
        }
        bf16x8 a_c, c_c, w0[3], w2[3];
        a_c = *(const bf16x8*)&hb0[p][l16][quad * 8];
        c_c = *(const bf16x8*)&hb1[p][l16][quad * 8];
#pragma unroll
        for (int g = 0; g < 3; ++g) {
            w0[g] = *(const bf16x8*)(pW0 + g * 512);
            w2[g] = *(const bf16x8*)(pW2 + g * 512);
        }
#pragma unroll
        for (int kk = 0; kk < 8; ++kk) {
            bf16x8 a_n, c_n, w0n[3], w2n[3];
            if (kk < 7) {
                a_n = *(const bf16x8*)&hb0[p][l16][(kk + 1) * 32 + quad * 8];
                c_n = *(const bf16x8*)&hb1[p][l16][(kk + 1) * 32 + quad * 8];
#pragma unroll
                for (int g = 0; g < 3; ++g) {
                    w0n[g] = *(const bf16x8*)(pW0 + ((kk + 1) * 3 + g) * 512);
                    w2n[g] = *(const bf16x8*)(pW2 + ((kk + 1) * 3 + g) * 512);
                }
            }
#pragma unroll
            for (int g = 0; g < 3; ++g) {
                g0[g] = MFMA16(a_c, w0[g], g0[g]);
                g1[g] = MFMA16(c_c, w2[g], g1[g]);
            }
            if (kk < 7) {
                a_c = a_n; c_c = c_n;
#pragma unroll
                for (int g = 0; g < 3; ++g) { w0[g] = w0n[g]; w2[g] = w2n[g]; }
            }
        }
        // layer-0 gates -> h0(t) into partner buffer
#pragma unroll
        for (int r = 0; r < 4; ++r) {
            float rr = sigm(cg[0][r] + g0[0][r] + bh0[0]);
            float zz = sigm(cg[1][r] + g0[1][r] + bh0[1]);
            float nn = tanhf(cg[2][r] + rr * (g0[2][r] + bh0[2]));
            h0m[r] = (1.0f - zz) * nn + zz * h0m[r];
            hb0[q][rw + r][col] = (bf16)h0m[r];
        }
        __syncthreads();   // B1: h0(t) visible; done with hb0[p]/hb1[p]

        // -------- phase B: gi1 = h0(t)@w_ih1^T; next-step cg overlapped ------
        int nid[4];
#pragma unroll
        for (int r = 0; r < 4; ++r)
            nid[r] = tgt[(row0 + rw + r) * 32 + t];   // char id for step t+1
        float cgn[3][4];
#pragma unroll
        for (int g = 0; g < 3; ++g)
#pragma unroll
            for (int r = 0; r < 4; ++r)
                cgn[g][r] = cproj[(size_t)nid[r] * 768 + g * 256 + col]
                          + gword[(size_t)(row0 + rw + r) * 768 + g * 256 + col];

        fx4 gi[3];
#pragma unroll
        for (int g = 0; g < 3; ++g) gi[g] = fx4{0.f, 0.f, 0.f, 0.f};
        bf16x8 b_c, w1[3];
        b_c = *(const bf16x8*)&hb0[q][l16][quad * 8];
#pragma unroll
        for (int g = 0; g < 3; ++g)
            w1[g] = *(const bf16x8*)(pW1 + g * 512);
#pragma unroll
        for (int kk = 0; kk < 8; ++kk) {
            bf16x8 b_n, w1n[3];
            if (kk < 7) {
                b_n = *(const bf16x8*)&hb0[q][l16][(kk + 1) * 32 + quad * 8];
#pragma unroll
                for (int g = 0; g < 3; ++g)
                    w1n[g] = *(const bf16x8*)(pW1 + ((kk + 1) * 3 + g) * 512);
            }
#pragma unroll
            for (int g = 0; g < 3; ++g)
                gi[g] = MFMA16(b_c, w1[g], gi[g]);
            if (kk < 7) {
                b_c = b_n;
#pragma unroll
                for (int g = 0; g < 3; ++g) w1[g] = w1n[g];
            }
        }
        // layer-1 gates (g1 = gh1 from phase A) -> h1(t)
#pragma unroll
        for (int r = 0; r < 4; ++r) {
            float rr = sigm(gi[0][r] + bi1[0] + g1[0][r] + bh1[0]);
            float zz = sigm(gi[1][r] + bi1[1] + g1[1][r] + bh1[1]);
            float nn = tanhf(gi[2][r] + bi1[2] + rr * (g1[2][r] + bh1[2]));
            h1m[r] = (1.0f - zz) * nn + zz * h1m[r];
            bf16 hv = (bf16)h1m[r];
            hb1[q][rw + r][col] = hv;
            __builtin_nontemporal_store(
                hv, &h1all[((size_t)(row0 + rw + r) * 32 + t) * 256 + col]);
        }
#pragma unroll
        for (int g = 0; g < 3; ++g)
#pragma unroll
            for (int r = 0; r < 4; ++r) cg[g][r] = cgn[g][r];

        __syncthreads();   // B2: h1(t) visible
    }
}

// ---------------------------------------------------------------------------
// Final logits: out[m,v] = (h1[m,:] + a2[m>>5,:]) @ pw^T + pb[v],  M=131072.
// ---------------------------------------------------------------------------
__global__ __launch_bounds__(256, 4) void logits_final(
    const bf16*  __restrict__ h1,    // (131072,256) bf16
    const float* __restrict__ a2,    // (4096,256) attn_out (fp32)
    const bf16*  __restrict__ pw,    // (256,256) bf16
    const float* __restrict__ pb,    // (256,)
    float* __restrict__ out)         // (131072,256)
{
    const int tid  = threadIdx.x;
    const int wid  = tid >> 6;
    const int lane = tid & 63;
    const int quad = lane >> 4;
    const int l16  = lane & 15;
    const int m0   = blockIdx.x * 32;
    const int n0   = wid * 64;
    const int b    = m0 >> 5;          // all 32 rows share one batch index

    fx4 acc[4][2];
#pragma unroll
    for (int j = 0; j < 4; ++j) {
        acc[j][0] = fx4{0.f, 0.f, 0.f, 0.f};
        acc[j][1] = fx4{0.f, 0.f, 0.f, 0.f};
    }

    for (int k0 = 0; k0 < 256; k0 += 32) {
        bf16x8 h0 = *(const bf16x8*)(h1 + (size_t)(m0 + l16) * 256 + k0 + quad * 8);
        bf16x8 h1v = *(const bf16x8*)(h1 + (size_t)(m0 + 16 + l16) * 256 + k0 + quad * 8);
        const float* ap = a2 + (size_t)b * 256 + k0 + quad * 8;
        bf16x8 a0 = addcvt8(h0, ap);
        bf16x8 a1 = addcvt8(h1v, ap);
#pragma unroll
        for (int j = 0; j < 4; ++j) {
            bf16x8 bb = *(const bf16x8*)(pw + (size_t)(n0 + j * 16 + l16) * 256 + k0 + quad * 8);
            acc[j][0] = MFMA16(a0, bb, acc[j][0]);
            acc[j][1] = MFMA16(a1, bb, acc[j][1]);
        }
    }

#pragma unroll
    for (int j = 0; j < 4; ++j) {
        int n = n0 + j * 16 + l16;
        float bv = pb[n];
#pragma unroll
        for (int rt = 0; rt < 2; ++rt)
#pragma unroll
            for (int r = 0; r < 4; ++r) {
                int m = m0 + rt * 16 + quad * 4 + r;
                out[(size_t)m * 256 + n] = acc[j][rt][r] + bv;
            }
    }
}

// ---------------------------------------------------------------------------
extern "C" void kernel_launch(void* const* d_in, const int* in_sizes, int n_in,
                              void* d_out, int out_size, void* d_ws, size_t ws_size,
                              hipStream_t stream)
{
    const float* eword      = (const float*)d_in[0];
    const int*   tgt        = (const int*)  d_in[1];
    const float* char_emb   = (const float*)d_in[2];
    const float* ew_w       = (const float*)d_in[3];
    const float* ew_b       = (const float*)d_in[4];
    const float* w_ih0      = (const float*)d_in[5];   // (768, 832)
    const float* w_hh0      = (const float*)d_in[6];
    const float* b_ih0      = (const float*)d_in[7];
    const float* b_hh0      = (const float*)d_in[8];
    const float* w_ih1      = (const float*)d_in[9];
    const float* w_hh1      = (const float*)d_in[10];
    const float* b_ih1      = (const float*)d_in[11];
    const float* b_hh1      = (const float*)d_in[12];
    const float* attn_in_w  = (const float*)d_in[13];  // wq|wk|wv (q,k dead)
    const float* attn_in_b  = (const float*)d_in[14];
    const float* attn_out_w = (const float*)d_in[15];
    const float* attn_out_b = (const float*)d_in[16];
    // d_in[17..18] key_w/key_b dead (len-1 softmax)
    const float* val_w      = (const float*)d_in[19];
    const float* val_b      = (const float*)d_in[20];
    const float* proj_w     = (const float*)d_in[21];
    const float* proj_b     = (const float*)d_in[22];

    char* ws = (char*)d_ws;
    float* h0i   = (float*)ws;  ws += (size_t)4096 * 256 * 4;   //  4 MB
    float* gwrd  = (float*)ws;  ws += (size_t)4096 * 768 * 4;   // 12 MB
    float* cproj = (float*)ws;  ws += (size_t)256  * 768 * 4;   // .75 MB
    float* a2    = (float*)ws;  ws += (size_t)4096 * 256 * 4;   //  4 MB
    float* buf1  = (float*)ws;  ws += (size_t)4096 * 256 * 4;   //  4 MB (t1)
    float* buf2  = (float*)ws;  ws += (size_t)4096 * 256 * 4;   //  4 MB (ev)
    bf16*  wbhh0 = (bf16*)ws;   ws += (size_t)768 * 256 * 2;    // packed slabs
    bf16*  wbih1 = (bf16*)ws;   ws += (size_t)768 * 256 * 2;
    bf16*  wbhh1 = (bf16*)ws;   ws += (size_t)768 * 256 * 2;
    bf16*  wbprj = (bf16*)ws;   ws += (size_t)256 * 256 * 2;
    bf16*  h1all = (bf16*)ws;   ws += (size_t)4096 * 32 * 256 * 2;  // 67 MB

    dim3 blk(256);
    // pack loop weights into per-wave linear slabs (bf16)
    wpack<<<dim3(96), blk, 0, stream>>>(w_hh0, wbhh0);
    wpack<<<dim3(96), blk, 0, stream>>>(w_ih1, wbih1);
    wpack<<<dim3(96), blk, 0, stream>>>(w_hh1, wbhh1);
    f2b<<<dim3(64),  blk, 0, stream>>>(proj_w, wbprj, 256 * 256);

    // h0 = tanh(eword @ ew_w^T + ew_b)
    gemm_bt<<<dim3(128, 1), blk, 0, stream>>>(eword, 768, ew_w, 768, ew_b, h0i, 256, 1, 768);
    // gword = eword @ w_ih0[:,64:]^T + b_ih0
    gemm_bt<<<dim3(128, 3), blk, 0, stream>>>(eword, 768, w_ih0 + 64, 832, b_ih0, gwrd, 768, 0, 768);
    // cproj = char_emb @ w_ih0[:,:64]^T   (PAD row of char_emb is zero)
    gemm_bt<<<dim3(8, 3),   blk, 0, stream>>>(char_emb, 64, w_ih0, 832, nullptr, cproj, 768, 0, 64);
    // attention chain (static): t1 = ew@vw^T+vb; ev = t1@wv^T+bv; a2 = ev@ao^T+ab
    gemm_bt<<<dim3(128, 1), blk, 0, stream>>>(eword, 768, val_w, 768, val_b, buf1, 256, 0, 768);
    gemm_bt<<<dim3(128, 1), blk, 0, stream>>>(buf1, 256, attn_in_w + 512 * 256, 256, attn_in_b + 512, buf2, 256, 0, 256);
    gemm_bt<<<dim3(128, 1), blk, 0, stream>>>(buf2, 256, attn_out_w, 256, attn_out_b, a2, 256, 0, 256);

    // recurrent decode (h1 trajectory to global), 256 blocks x 16 rows
    decoder_loop<<<dim3(256), dim3(1024), 0, stream>>>(
        tgt, h0i, gwrd, cproj,
        wbhh0, b_hh0, wbih1, b_ih1, wbhh1, b_hh1, h1all);

    // batched logits: out = (h1 + a2) @ pw^T + pb
    logits_final<<<dim3(4096), blk, 0, stream>>>(h1all, a2, wbprj, proj_b, (float*)d_out);
}